// Round 4
// baseline (65.854 us; speedup 1.0000x reference)
//
#include <hip/hip_runtime.h>
#include <math.h>

// OFDM: per-row 64-pt complex FFT (radix-2 DIF, lane-per-bin).
// Cross-lane: xor32 -> v_permlane32_swap, xor16 -> v_permlane16_swap,
// xor8 -> DPP row_ror:8, xor4 -> ds_swizzle, xor2/xor1 -> DPP quad_perm.
// Complex samples held as packed float2 -> v_pk_fma_f32 (VOP3P) halves VALU.
// Epilogue in bit-reversed domain; scatter-store restores natural order.

typedef float f32x2 __attribute__((ext_vector_type(2)));
typedef unsigned int u32x2 __attribute__((ext_vector_type(2)));

struct LaneConst {
    float twc[5];   // stage 0..4 twiddle cos (stage 5 twiddle == 1)
    f32x2 tws2[5];  // stage 0..4 {-sin, +sin}
    float sgn[6];   // butterfly sign (+1 lower partner, -1 upper)
    float w0, w1, w2, w3; // pilot interp weights for this lane's natural bin
    int   kk;       // natural bin index = brev6(lane)
};

__device__ __forceinline__ f32x2 pk_fma(f32x2 a, f32x2 b, f32x2 c) {
#if __has_builtin(__builtin_elementwise_fma)
    return __builtin_elementwise_fma(a, b, c);
#else
    return a * b + c;  // fp-contract=fast -> v_pk_fma_f32
#endif
}

template <int CTRL>
__device__ __forceinline__ float dpp_mov(float x) {
    return __int_as_float(__builtin_amdgcn_update_dpp(
        0, __float_as_int(x), CTRL, 0xF, 0xF, true));
}

__device__ __forceinline__ float rdlane(float x, int l) {
    return __int_as_float(__builtin_amdgcn_readlane(__float_as_int(x), l));
}

// butterfly via permlane32_swap: result = sgn*hiDup + loDup
__device__ __forceinline__ f32x2 bfly32(f32x2 z, float sgn) {
    u32x2 tr = __builtin_amdgcn_permlane32_swap(
        (unsigned)__float_as_int(z.x), (unsigned)__float_as_int(z.x), false, false);
    u32x2 ti = __builtin_amdgcn_permlane32_swap(
        (unsigned)__float_as_int(z.y), (unsigned)__float_as_int(z.y), false, false);
    f32x2 lo = { __int_as_float((int)tr[0]), __int_as_float((int)ti[0]) };
    f32x2 hi = { __int_as_float((int)tr[1]), __int_as_float((int)ti[1]) };
    return pk_fma((f32x2){sgn, sgn}, hi, lo);
}

__device__ __forceinline__ f32x2 bfly16(f32x2 z, float sgn) {
    u32x2 tr = __builtin_amdgcn_permlane16_swap(
        (unsigned)__float_as_int(z.x), (unsigned)__float_as_int(z.x), false, false);
    u32x2 ti = __builtin_amdgcn_permlane16_swap(
        (unsigned)__float_as_int(z.y), (unsigned)__float_as_int(z.y), false, false);
    f32x2 lo = { __int_as_float((int)tr[0]), __int_as_float((int)ti[0]) };
    f32x2 hi = { __int_as_float((int)tr[1]), __int_as_float((int)ti[1]) };
    return pk_fma((f32x2){sgn, sgn}, hi, lo);
}

template <int CTRL>
__device__ __forceinline__ f32x2 bfly_dpp(f32x2 z, float sgn) {
    f32x2 p = { dpp_mov<CTRL>(z.x), dpp_mov<CTRL>(z.y) };
    return pk_fma((f32x2){sgn, sgn}, z, p);   // sgn*mine + partner
}

__device__ __forceinline__ f32x2 bfly_swz4(f32x2 z, float sgn) {
    f32x2 p;
    p.x = __int_as_float(__builtin_amdgcn_ds_swizzle(__float_as_int(z.x), 0x101F));
    p.y = __int_as_float(__builtin_amdgcn_ds_swizzle(__float_as_int(z.y), 0x101F));
    return pk_fma((f32x2){sgn, sgn}, z, p);
}

// complex multiply by twiddle (twc, {-tws,+tws}): 2 packed ops
__device__ __forceinline__ f32x2 cmul_tw(f32x2 a, float twc, f32x2 tws2) {
    f32x2 t = a * (f32x2){twc, twc};     // (ar*c, ai*c)
    return pk_fma(a.yx, tws2, t);        // (ar*c - ai*s, ai*c + ar*s)
}

template <int R>
__device__ __forceinline__ void load_block(f32x2* z, const float* __restrict__ x,
                                           int r0, int lane) {
    #pragma unroll
    for (int j = 0; j < R; ++j) {
        const float* px = x + (size_t)(r0 + j) * 128;
        z[j].x = px[lane];
        z[j].y = px[64 + lane];
    }
}

template <int R>
__device__ __forceinline__ void process_block(f32x2* z, float* __restrict__ out,
                                              int r0, int lane, const LaneConst& c) {
    #pragma unroll
    for (int j = 0; j < R; ++j) {
        f32x2 v = z[j];
        v = bfly32(v, c.sgn[0]);        v = cmul_tw(v, c.twc[0], c.tws2[0]);
        v = bfly16(v, c.sgn[1]);        v = cmul_tw(v, c.twc[1], c.tws2[1]);
        v = bfly_dpp<0x128>(v, c.sgn[2]); v = cmul_tw(v, c.twc[2], c.tws2[2]); // row_ror:8 = xor8
        v = bfly_swz4(v, c.sgn[3]);     v = cmul_tw(v, c.twc[3], c.tws2[3]);   // xor4
        v = bfly_dpp<0x4E>(v, c.sgn[4]); v = cmul_tw(v, c.twc[4], c.tws2[4]);  // xor2
        v = bfly_dpp<0xB1>(v, c.sgn[5]);                                        // xor1, tw==1
        z[j] = v;
    }
    // epilogue: pilots F[11],F[25],F[39],F[53] live at lanes 52,38,57,43 (brev6)
    #pragma unroll
    for (int j = 0; j < R; ++j) {
        const f32x2 f = z[j];
        const float p0r = rdlane(f.x, 52), p0i = rdlane(f.y, 52);
        const float p1r = rdlane(f.x, 38), p1i = rdlane(f.y, 38);
        const float p2r = rdlane(f.x, 57), p2i = rdlane(f.y, 57);
        const float p3r = rdlane(f.x, 43), p3i = rdlane(f.y, 43);
        f32x2 h = (f32x2){c.w0, c.w0} * (f32x2){p0r, p0i};
        h = pk_fma((f32x2){c.w1, c.w1}, (f32x2){p1r, p1i}, h);
        h = pk_fma((f32x2){c.w2, c.w2}, (f32x2){p2r, p2i}, h);
        h = pk_fma((f32x2){c.w3, c.w3}, (f32x2){p3r, p3i}, h);
        const float denom = fmaf(h.x, h.x, fmaf(h.y, h.y, 1e-8f));
        const float rd = __builtin_amdgcn_rcpf(denom);
        f32x2 num = f * (f32x2){h.x, h.x};          // (fr*hr, fi*hr)
        num = pk_fma(f.yx, (f32x2){h.y, -h.y}, num); // (+fi*hi, -fr*hi)
        const f32x2 eq = num * (f32x2){rd, rd};
        float* po = out + (size_t)(r0 + j) * 128;
        __builtin_nontemporal_store(eq.x, po + c.kk);
        __builtin_nontemporal_store(eq.y, po + 64 + c.kk);
    }
}

__global__ __launch_bounds__(256) void ofdm_kernel(const float* __restrict__ x,
                                                   float* __restrict__ out,
                                                   int nrows) {
    const int lane = threadIdx.x & 63;
    const int wid  = threadIdx.x >> 6;
    const int wavesPerBlock = blockDim.x >> 6;
    const int gw = blockIdx.x * wavesPerBlock + wid;
    const int gstride = gridDim.x * wavesPerBlock;

    LaneConst c;
    #pragma unroll
    for (int s = 0; s < 6; ++s) {
        const int half = 32 >> s;
        const bool up = (lane & half) != 0;
        c.sgn[s] = up ? -1.0f : 1.0f;
        if (s < 5) {
            const int t = (lane & (half - 1)) << s;
            const float th = (float)t * 0.0981747704246810387f; // pi/32
            const float cc = up ? cosf(th) : 1.0f;
            const float ss = up ? -sinf(th) : 0.0f;  // W = e^{-i th}
            c.twc[s] = cc;
            c.tws2[s] = (f32x2){-ss, ss};
        }
    }
    c.kk = (int)(__brev((unsigned)lane) >> 26);
    const int seg = (c.kk <= 25) ? 0 : (c.kk <= 39) ? 1 : 2; // pilots 11,25,39,53
    float a = (float)(c.kk - (11 + seg * 14)) * (1.0f / 14.0f);
    a = fminf(fmaxf(a, 0.0f), 1.0f);
    c.w0 = c.w1 = c.w2 = c.w3 = 0.0f;
    const float wa = 1.0f - a, wb = a;
    if (seg == 0) { c.w0 = wa; c.w1 = wb; }
    else if (seg == 1) { c.w1 = wa; c.w2 = wb; }
    else { c.w2 = wa; c.w3 = wb; }

    constexpr int R = 8;
    const int B = nrows / R;               // full 8-row blocks
    int b = gw;
    if (b < B) {
        f32x2 cur[R];
        load_block<R>(cur, x, b * R, lane);
        for (;;) {
            const int bn = b + gstride;
            const bool more = (bn < B);
            f32x2 nxt[R];
            if (more) load_block<R>(nxt, x, bn * R, lane);   // prefetch next block
            process_block<R>(cur, out, b * R, lane, c);
            if (!more) break;
            #pragma unroll
            for (int j = 0; j < R; ++j) cur[j] = nxt[j];
            b = bn;
        }
    }
    // tail rows (none when nrows % 8 == 0)
    for (int rr = B * R + gw; rr < nrows; rr += gstride) {
        f32x2 one[1];
        load_block<1>(one, x, rr, lane);
        process_block<1>(one, out, rr, lane, c);
    }
}

extern "C" void kernel_launch(void* const* d_in, const int* in_sizes, int n_in,
                              void* d_out, int out_size, void* d_ws, size_t ws_size,
                              hipStream_t stream) {
    const float* x = (const float*)d_in[0];
    float* out = (float*)d_out;
    const int nrows = in_sizes[0] / 128;   // 262144
    const int block = 256;                 // 4 waves/block
    const int grid = 2048;                 // 8192 waves, 4 blocks of 8 rows each
    hipLaunchKernelGGL(ofdm_kernel, dim3(grid), dim3(block), 0, stream,
                       x, out, nrows);
}

// Round 5
// 48.517 us; speedup vs baseline: 1.3573x; 1.3573x over previous
//
#include <hip/hip_runtime.h>
#include <math.h>

// OFDM: per-row 64-pt complex FFT (radix-2 DIF, lane-per-bin).
// Cross-lane: xor32 -> v_permlane32_swap, xor16 -> v_permlane16_swap,
// xor8 -> DPP row_ror:8, xor4 -> ds_swizzle, xor2/xor1 -> DPP quad_perm.
// Scalar float math (R2 structure — packed f32x2 regressed in R3).
// Epilogue in bit-reversed domain; scatter-store restores natural order.

typedef unsigned int uint2v __attribute__((ext_vector_type(2)));

struct LaneConst {
    float twc[5], tws[5]; // stage 0..4 twiddles (stage 5 twiddle == 1)
    float sgn[6];         // butterfly sign (+1 lower partner, -1 upper)
    float w0, w1, w2, w3; // pilot interpolation weights for this lane
    int   kk;             // natural bin index = brev6(lane)
};

template <int CTRL>
__device__ __forceinline__ float dpp_mov(float x) {
    return __int_as_float(__builtin_amdgcn_update_dpp(
        0, __float_as_int(x), CTRL, 0xF, 0xF, true));
}

__device__ __forceinline__ float rdlane(float x, int l) {
    return __int_as_float(__builtin_amdgcn_readlane(__float_as_int(x), l));
}

template <int R>
__device__ __forceinline__ void do_rows(const float* __restrict__ x,
                                        float* __restrict__ out,
                                        int r0, int lane, const LaneConst& c) {
    float xr[R], xi[R];
    #pragma unroll
    for (int j = 0; j < R; ++j) {
        const float* px = x + (size_t)(r0 + j) * 128;
        xr[j] = px[lane];
        xi[j] = px[64 + lane];
    }

    #pragma unroll
    for (int j = 0; j < R; ++j) {
        float ar, ai, t;
        // ---- stage 0: xor32 via permlane32_swap (VALU) ----
        {
            uint2v tr = __builtin_amdgcn_permlane32_swap(
                (unsigned)__float_as_int(xr[j]), (unsigned)__float_as_int(xr[j]), false, false);
            uint2v ti = __builtin_amdgcn_permlane32_swap(
                (unsigned)__float_as_int(xi[j]), (unsigned)__float_as_int(xi[j]), false, false);
            ar = fmaf(c.sgn[0], __int_as_float((int)tr[1]), __int_as_float((int)tr[0]));
            ai = fmaf(c.sgn[0], __int_as_float((int)ti[1]), __int_as_float((int)ti[0]));
        }
        t = fmaf(ar, c.twc[0], -(ai * c.tws[0]));
        xi[j] = fmaf(ar, c.tws[0], ai * c.twc[0]);
        xr[j] = t;

        // ---- stage 1: xor16 via permlane16_swap (VALU) ----
        {
            uint2v tr = __builtin_amdgcn_permlane16_swap(
                (unsigned)__float_as_int(xr[j]), (unsigned)__float_as_int(xr[j]), false, false);
            uint2v ti = __builtin_amdgcn_permlane16_swap(
                (unsigned)__float_as_int(xi[j]), (unsigned)__float_as_int(xi[j]), false, false);
            ar = fmaf(c.sgn[1], __int_as_float((int)tr[1]), __int_as_float((int)tr[0]));
            ai = fmaf(c.sgn[1], __int_as_float((int)ti[1]), __int_as_float((int)ti[0]));
        }
        t = fmaf(ar, c.twc[1], -(ai * c.tws[1]));
        xi[j] = fmaf(ar, c.tws[1], ai * c.twc[1]);
        xr[j] = t;

        // ---- stage 2: xor8 via DPP row_ror:8 (within 16-lane row, (i+8)%16 == i^8) ----
        {
            const float pr  = dpp_mov<0x128>(xr[j]);
            const float pi_ = dpp_mov<0x128>(xi[j]);
            ar = fmaf(c.sgn[2], xr[j], pr);
            ai = fmaf(c.sgn[2], xi[j], pi_);
        }
        t = fmaf(ar, c.twc[2], -(ai * c.tws[2]));
        xi[j] = fmaf(ar, c.tws[2], ai * c.twc[2]);
        xr[j] = t;

        // ---- stage 3: xor4 via ds_swizzle ----
        {
            float pr = __int_as_float(__builtin_amdgcn_ds_swizzle(__float_as_int(xr[j]), 0x101F));
            float pi_ = __int_as_float(__builtin_amdgcn_ds_swizzle(__float_as_int(xi[j]), 0x101F));
            ar = fmaf(c.sgn[3], xr[j], pr);
            ai = fmaf(c.sgn[3], xi[j], pi_);
        }
        t = fmaf(ar, c.twc[3], -(ai * c.tws[3]));
        xi[j] = fmaf(ar, c.tws[3], ai * c.twc[3]);
        xr[j] = t;

        // ---- stage 4: xor2 via DPP quad_perm [2,3,0,1] = 0x4E ----
        ar = fmaf(c.sgn[4], xr[j], dpp_mov<0x4E>(xr[j]));
        ai = fmaf(c.sgn[4], xi[j], dpp_mov<0x4E>(xi[j]));
        t = fmaf(ar, c.twc[4], -(ai * c.tws[4]));
        xi[j] = fmaf(ar, c.tws[4], ai * c.twc[4]);
        xr[j] = t;

        // ---- stage 5: xor1 via DPP quad_perm [1,0,3,2] = 0xB1; twiddle == 1 ----
        ar = fmaf(c.sgn[5], xr[j], dpp_mov<0xB1>(xr[j]));
        ai = fmaf(c.sgn[5], xi[j], dpp_mov<0xB1>(xi[j]));
        xr[j] = ar;
        xi[j] = ai;
    }

    // ---- epilogue per row, scrambled domain ----
    // F[11]@lane52, F[25]@lane38, F[39]@lane57, F[53]@lane43 (brev6)
    #pragma unroll
    for (int j = 0; j < R; ++j) {
        const float h0r = rdlane(xr[j], 52), h0i = rdlane(xi[j], 52);
        const float h1r = rdlane(xr[j], 38), h1i = rdlane(xi[j], 38);
        const float h2r = rdlane(xr[j], 57), h2i = rdlane(xi[j], 57);
        const float h3r = rdlane(xr[j], 43), h3i = rdlane(xi[j], 43);
        float hr = c.w0 * h0r;
        hr = fmaf(c.w1, h1r, hr);
        hr = fmaf(c.w2, h2r, hr);
        hr = fmaf(c.w3, h3r, hr);
        float hi = c.w0 * h0i;
        hi = fmaf(c.w1, h1i, hi);
        hi = fmaf(c.w2, h2i, hi);
        hi = fmaf(c.w3, h3i, hi);
        const float denom = fmaf(hr, hr, fmaf(hi, hi, 1e-8f));
        const float rd = __builtin_amdgcn_rcpf(denom);
        const float eqr = fmaf(xr[j], hr,  xi[j] * hi) * rd;
        const float eqi = fmaf(xi[j], hr, -(xr[j] * hi)) * rd;
        float* po = out + (size_t)(r0 + j) * 128;
        __builtin_nontemporal_store(eqr, po + c.kk);
        __builtin_nontemporal_store(eqi, po + 64 + c.kk);
    }
}

__global__ __launch_bounds__(256) void ofdm_kernel(const float* __restrict__ x,
                                                   float* __restrict__ out,
                                                   int nrows) {
    const int lane = threadIdx.x & 63;
    const int wid  = threadIdx.x >> 6;
    const int wavesPerBlock = blockDim.x >> 6;
    const int gw = blockIdx.x * wavesPerBlock + wid;
    const int gstride = gridDim.x * wavesPerBlock;

    LaneConst c;
    #pragma unroll
    for (int s = 0; s < 6; ++s) {
        const int half = 32 >> s;
        const bool up = (lane & half) != 0;
        c.sgn[s] = up ? -1.0f : 1.0f;
        if (s < 5) {
            const int t = (lane & (half - 1)) << s;
            const float th = (float)t * 0.0981747704246810387f; // pi/32
            c.twc[s] = up ? cosf(th) : 1.0f;
            c.tws[s] = up ? -sinf(th) : 0.0f;   // W = e^{-i th}
        }
    }
    c.kk = (int)(__brev((unsigned)lane) >> 26);
    const int seg = (c.kk <= 25) ? 0 : (c.kk <= 39) ? 1 : 2; // pilots 11,25,39,53
    float a = (float)(c.kk - (11 + seg * 14)) * (1.0f / 14.0f);
    a = fminf(fmaxf(a, 0.0f), 1.0f);
    c.w0 = c.w1 = c.w2 = c.w3 = 0.0f;
    const float wa = 1.0f - a, wb = a;
    if (seg == 0) { c.w0 = wa; c.w1 = wb; }
    else if (seg == 1) { c.w1 = wa; c.w2 = wb; }
    else { c.w2 = wa; c.w3 = wb; }

    constexpr int R = 8;
    const int step = gstride * R;
    int r = gw * R;
    for (; r + R <= nrows; r += step)
        do_rows<R>(x, out, r, lane, c);
    for (; r < nrows; ++r)
        do_rows<1>(x, out, r, lane, c);
}

extern "C" void kernel_launch(void* const* d_in, const int* in_sizes, int n_in,
                              void* d_out, int out_size, void* d_ws, size_t ws_size,
                              hipStream_t stream) {
    const float* x = (const float*)d_in[0];
    float* out = (float*)d_out;
    const int nrows = in_sizes[0] / 128;   // 262144
    const int block = 256;                 // 4 waves/block
    const int grid = 2048;                 // 8192 waves, 4 iters x 8 rows
    hipLaunchKernelGGL(ofdm_kernel, dim3(grid), dim3(block), 0, stream,
                       x, out, nrows);
}

// Round 7
// 46.785 us; speedup vs baseline: 1.4076x; 1.0370x over previous
//
#include <hip/hip_runtime.h>
#include <math.h>

// OFDM: per-row 64-pt complex FFT (radix-2 DIF, lane-per-bin).
// Stages 0-1: scalar, permlane32/16_swap (VALU). Stages 2-5 + epilogue:
// row-PAIR packed in f32x2 using compiler-generated packed math
// (__builtin_elementwise_fma -> v_pk_fma_f32; NO inline asm — R5 failed on
// the DPP-after-inline-asm hazard: LLVM only inserts DPP wait-state nops for
// recognized VALU producers). Cross-lane per 32-bit component: xor8 -> DPP
// row_ror:8, xor4 -> ds_swizzle, xor2/xor1 -> DPP quad_perm.
// Epilogue in bit-reversed domain; scatter-store restores natural order.

typedef float f32x2 __attribute__((ext_vector_type(2)));
typedef unsigned int uint2v __attribute__((ext_vector_type(2)));

struct LaneConst {
    float twc0, tws0, twc1, tws1, sgn0, sgn1;  // scalar stages 0,1
    f32x2 psgn[4];            // stages 2..5 butterfly sign (broadcast pair)
    f32x2 C[3], S[3], Sn[3];  // stages 2..4 twiddle (stage 5 twiddle == 1)
    f32x2 pw0, pw1, pw2, pw3; // pilot interp weights (broadcast pair)
    int   kk;                 // natural bin index = brev6(lane)
};

__device__ __forceinline__ f32x2 pk_fma(f32x2 a, f32x2 b, f32x2 cc) {
#if __has_builtin(__builtin_elementwise_fma)
    return __builtin_elementwise_fma(a, b, cc);
#else
    return a * b + cc;   // fp-contract=fast
#endif
}

template <int CTRL>
__device__ __forceinline__ float dpp_mov(float x) {
    return __int_as_float(__builtin_amdgcn_update_dpp(
        0, __float_as_int(x), CTRL, 0xF, 0xF, true));
}
__device__ __forceinline__ float swz4(float x) {
    return __int_as_float(__builtin_amdgcn_ds_swizzle(__float_as_int(x), 0x101F));
}
__device__ __forceinline__ float rdlane(float x, int l) {
    return __int_as_float(__builtin_amdgcn_readlane(__float_as_int(x), l));
}

// scalar stage 0 (xor32) + stage 1 (xor16) — proven in R2/R4
__device__ __forceinline__ void stage01(float& xr, float& xi, const LaneConst& c) {
    float ar, ai, t;
    {
        uint2v tr = __builtin_amdgcn_permlane32_swap(
            (unsigned)__float_as_int(xr), (unsigned)__float_as_int(xr), false, false);
        uint2v ti = __builtin_amdgcn_permlane32_swap(
            (unsigned)__float_as_int(xi), (unsigned)__float_as_int(xi), false, false);
        ar = fmaf(c.sgn0, __int_as_float((int)tr[1]), __int_as_float((int)tr[0]));
        ai = fmaf(c.sgn0, __int_as_float((int)ti[1]), __int_as_float((int)ti[0]));
    }
    t  = fmaf(ar, c.twc0, -(ai * c.tws0));
    xi = fmaf(ar, c.tws0, ai * c.twc0);
    xr = t;
    {
        uint2v tr = __builtin_amdgcn_permlane16_swap(
            (unsigned)__float_as_int(xr), (unsigned)__float_as_int(xr), false, false);
        uint2v ti = __builtin_amdgcn_permlane16_swap(
            (unsigned)__float_as_int(xi), (unsigned)__float_as_int(xi), false, false);
        ar = fmaf(c.sgn1, __int_as_float((int)tr[1]), __int_as_float((int)tr[0]));
        ai = fmaf(c.sgn1, __int_as_float((int)ti[1]), __int_as_float((int)ti[0]));
    }
    t  = fmaf(ar, c.twc1, -(ai * c.tws1));
    xi = fmaf(ar, c.tws1, ai * c.twc1);
    xr = t;
}

// packed stages 2..5 + epilogue for a row pair (rows r0, r0+1 in .x/.y).
// STORE_PAIR=false stores only the .x row (odd-tail case).
template <bool STORE_PAIR>
__device__ __forceinline__ void pair_tail(f32x2 zr, f32x2 zi,
                                          float* __restrict__ out,
                                          int r0, const LaneConst& c) {
    f32x2 pr, pi, ar, ai;
    // ---- stage 2: xor8 via DPP row_ror:8 ----
    pr.x = dpp_mov<0x128>(zr.x); pr.y = dpp_mov<0x128>(zr.y);
    pi.x = dpp_mov<0x128>(zi.x); pi.y = dpp_mov<0x128>(zi.y);
    ar = pk_fma(c.psgn[0], zr, pr);
    ai = pk_fma(c.psgn[0], zi, pi);
    zr = pk_fma(ar, c.C[0], ai * c.Sn[0]);
    zi = pk_fma(ai, c.C[0], ar * c.S[0]);
    // ---- stage 3: xor4 via ds_swizzle ----
    pr.x = swz4(zr.x); pr.y = swz4(zr.y);
    pi.x = swz4(zi.x); pi.y = swz4(zi.y);
    ar = pk_fma(c.psgn[1], zr, pr);
    ai = pk_fma(c.psgn[1], zi, pi);
    zr = pk_fma(ar, c.C[1], ai * c.Sn[1]);
    zi = pk_fma(ai, c.C[1], ar * c.S[1]);
    // ---- stage 4: xor2 via DPP quad_perm [2,3,0,1] ----
    pr.x = dpp_mov<0x4E>(zr.x); pr.y = dpp_mov<0x4E>(zr.y);
    pi.x = dpp_mov<0x4E>(zi.x); pi.y = dpp_mov<0x4E>(zi.y);
    ar = pk_fma(c.psgn[2], zr, pr);
    ai = pk_fma(c.psgn[2], zi, pi);
    zr = pk_fma(ar, c.C[2], ai * c.Sn[2]);
    zi = pk_fma(ai, c.C[2], ar * c.S[2]);
    // ---- stage 5: xor1 via DPP quad_perm [1,0,3,2]; twiddle == 1 ----
    pr.x = dpp_mov<0xB1>(zr.x); pr.y = dpp_mov<0xB1>(zr.y);
    pi.x = dpp_mov<0xB1>(zi.x); pi.y = dpp_mov<0xB1>(zi.y);
    zr = pk_fma(c.psgn[3], zr, pr);
    zi = pk_fma(c.psgn[3], zi, pi);

    // ---- epilogue (scrambled domain): pilots at lanes 52,38,57,43 ----
    f32x2 p0r = { rdlane(zr.x, 52), rdlane(zr.y, 52) };
    f32x2 p0i = { rdlane(zi.x, 52), rdlane(zi.y, 52) };
    f32x2 p1r = { rdlane(zr.x, 38), rdlane(zr.y, 38) };
    f32x2 p1i = { rdlane(zi.x, 38), rdlane(zi.y, 38) };
    f32x2 p2r = { rdlane(zr.x, 57), rdlane(zr.y, 57) };
    f32x2 p2i = { rdlane(zi.x, 57), rdlane(zi.y, 57) };
    f32x2 p3r = { rdlane(zr.x, 43), rdlane(zr.y, 43) };
    f32x2 p3i = { rdlane(zi.x, 43), rdlane(zi.y, 43) };
    f32x2 hr = c.pw0 * p0r;
    hr = pk_fma(c.pw1, p1r, hr);
    hr = pk_fma(c.pw2, p2r, hr);
    hr = pk_fma(c.pw3, p3r, hr);
    f32x2 hi = c.pw0 * p0i;
    hi = pk_fma(c.pw1, p1i, hi);
    hi = pk_fma(c.pw2, p2i, hi);
    hi = pk_fma(c.pw3, p3i, hi);
    f32x2 den = pk_fma(hr, hr, pk_fma(hi, hi, (f32x2){1e-8f, 1e-8f}));
    f32x2 rd;
    rd.x = __builtin_amdgcn_rcpf(den.x);
    rd.y = __builtin_amdgcn_rcpf(den.y);
    f32x2 numr = pk_fma(zr, hr, zi * hi);
    f32x2 numi = pk_fma(zi, hr, zr * (-hi));
    f32x2 eqr = numr * rd;
    f32x2 eqi = numi * rd;
    float* po0 = out + (size_t)r0 * 128;
    __builtin_nontemporal_store(eqr.x, po0 + c.kk);
    __builtin_nontemporal_store(eqi.x, po0 + 64 + c.kk);
    if (STORE_PAIR) {
        float* po1 = po0 + 128;
        __builtin_nontemporal_store(eqr.y, po1 + c.kk);
        __builtin_nontemporal_store(eqi.y, po1 + 64 + c.kk);
    }
}

__device__ __forceinline__ void do_rows8(const float* __restrict__ x,
                                         float* __restrict__ out,
                                         int r0, int lane, const LaneConst& c) {
    float xr[8], xi[8];
    #pragma unroll
    for (int j = 0; j < 8; ++j) {
        const float* px = x + (size_t)(r0 + j) * 128;
        xr[j] = px[lane];
        xi[j] = px[64 + lane];
    }
    #pragma unroll
    for (int j = 0; j < 8; ++j)
        stage01(xr[j], xi[j], c);
    #pragma unroll
    for (int p = 0; p < 4; ++p) {
        f32x2 zr = { xr[2 * p], xr[2 * p + 1] };
        f32x2 zi = { xi[2 * p], xi[2 * p + 1] };
        pair_tail<true>(zr, zi, out, r0 + 2 * p, c);
    }
}

__global__ __launch_bounds__(256) void ofdm_kernel(const float* __restrict__ x,
                                                   float* __restrict__ out,
                                                   int nrows) {
    const int lane = threadIdx.x & 63;
    const int wid  = threadIdx.x >> 6;
    const int wavesPerBlock = blockDim.x >> 6;
    const int gw = blockIdx.x * wavesPerBlock + wid;
    const int gstride = gridDim.x * wavesPerBlock;

    LaneConst c;
    {
        const bool up0 = (lane & 32) != 0;
        const float th0 = (float)(lane & 31) * 0.0981747704246810387f; // pi/32
        c.twc0 = up0 ? cosf(th0) : 1.0f;
        c.tws0 = up0 ? -sinf(th0) : 0.0f;
        c.sgn0 = up0 ? -1.0f : 1.0f;
        const bool up1 = (lane & 16) != 0;
        const float th1 = (float)((lane & 15) << 1) * 0.0981747704246810387f;
        c.twc1 = up1 ? cosf(th1) : 1.0f;
        c.tws1 = up1 ? -sinf(th1) : 0.0f;
        c.sgn1 = up1 ? -1.0f : 1.0f;
        #pragma unroll
        for (int s = 2; s < 6; ++s) {
            const int half = 32 >> s;
            const bool up = (lane & half) != 0;
            const float sg = up ? -1.0f : 1.0f;
            c.psgn[s - 2] = (f32x2){sg, sg};
            if (s < 5) {
                const int t = (lane & (half - 1)) << s;
                const float th = (float)t * 0.0981747704246810387f;
                const float cc = up ? cosf(th) : 1.0f;
                const float ss = up ? -sinf(th) : 0.0f;  // W = e^{-i th}
                c.C[s - 2]  = (f32x2){cc, cc};
                c.S[s - 2]  = (f32x2){ss, ss};
                c.Sn[s - 2] = (f32x2){-ss, -ss};
            }
        }
    }
    c.kk = (int)(__brev((unsigned)lane) >> 26);
    const int seg = (c.kk <= 25) ? 0 : (c.kk <= 39) ? 1 : 2; // pilots 11,25,39,53
    float a = (float)(c.kk - (11 + seg * 14)) * (1.0f / 14.0f);
    a = fminf(fmaxf(a, 0.0f), 1.0f);
    float w0 = 0, w1 = 0, w2 = 0, w3 = 0;
    const float wa = 1.0f - a, wb = a;
    if (seg == 0) { w0 = wa; w1 = wb; }
    else if (seg == 1) { w1 = wa; w2 = wb; }
    else { w2 = wa; w3 = wb; }
    c.pw0 = (f32x2){w0, w0}; c.pw1 = (f32x2){w1, w1};
    c.pw2 = (f32x2){w2, w2}; c.pw3 = (f32x2){w3, w3};

    const int step = gstride * 8;
    int r = gw * 8;
    for (; r + 8 <= nrows; r += step)
        do_rows8(x, out, r, lane, c);

    // tail (unused for nrows % 8 == 0): strided row pairs, then odd row
    const int tail = nrows & ~7;
    for (int rr = tail + gw * 2; rr + 2 <= nrows; rr += gstride * 2) {
        const float* p0 = x + (size_t)rr * 128;
        float xr0 = p0[lane],        xi0 = p0[64 + lane];
        float xr1 = p0[128 + lane],  xi1 = p0[192 + lane];
        stage01(xr0, xi0, c);
        stage01(xr1, xi1, c);
        pair_tail<true>((f32x2){xr0, xr1}, (f32x2){xi0, xi1}, out, rr, c);
    }
    if ((nrows & 1) && gw == 0) {
        const int rr = nrows - 1;
        const float* p0 = x + (size_t)rr * 128;
        float xr0 = p0[lane], xi0 = p0[64 + lane];
        stage01(xr0, xi0, c);
        pair_tail<false>((f32x2){xr0, xr0}, (f32x2){xi0, xi0}, out, rr, c);
    }
}

extern "C" void kernel_launch(void* const* d_in, const int* in_sizes, int n_in,
                              void* d_out, int out_size, void* d_ws, size_t ws_size,
                              hipStream_t stream) {
    const float* x = (const float*)d_in[0];
    float* out = (float*)d_out;
    const int nrows = in_sizes[0] / 128;   // 262144
    const int block = 256;                 // 4 waves/block
    const int grid = 2048;                 // 8192 waves, 4 iters x 8 rows
    hipLaunchKernelGGL(ofdm_kernel, dim3(grid), dim3(block), 0, stream,
                       x, out, nrows);
}